// Round 6
// baseline (698.635 us; speedup 1.0000x reference)
//
#include <hip/hip_runtime.h>
#include <math.h>

// R5 resubmission of the R4 minimal-osc kernel. Semantics identical; edits
// are defensive only: no forced launch-bounds occupancy cap, no register
// preload array, refreshed source hash.

#define BATCH    32
#define CHUNK    128
#define NCHUNK   500                      // 64000 / 128
#define NCH_TOT  (BATCH * NCHUNK)         // 16000 chunks
#define TAB_N    1152                     // entries 0..1024 used; rest pad

// ---------------------------------------------------------------------------
// exact scale function: 2 * sigmoid(x)^ln(10) + 1e-7 = 2*(1+e^-x)^(-ln10)+1e-7
// ---------------------------------------------------------------------------
__device__ __forceinline__ float scale_fn(float x) {
    float e = exp2f(-1.4426950408889634f * x);       // e^{-x}
    float l = log2f(1.0f + e);
    return 2.0f * exp2f(-2.302585092994046f * l) + 1e-7f;
}

// ---------------------------------------------------------------------------
// Kernel 1: per-chunk sums of f0 in double.
// ---------------------------------------------------------------------------
__global__ __launch_bounds__(128) void chunk_sum_kernel(
        const float* __restrict__ f0, double* __restrict__ csum) {
    int bx = blockIdx.x;
    int t  = threadIdx.x;
    double v = (double)f0[(long)bx * CHUNK + t];
    for (int off = 32; off > 0; off >>= 1) v += __shfl_down(v, off, 64);
    __shared__ double ws[2];
    if ((t & 63) == 0) ws[t >> 6] = v;
    __syncthreads();
    if (t == 0) csum[bx] = ws[0] + ws[1];
}

// ---------------------------------------------------------------------------
// Kernel 2: per-row EXCLUSIVE scan of the NCHUNK chunk sums (in place).
// ---------------------------------------------------------------------------
__global__ __launch_bounds__(512) void chunk_scan_kernel(double* __restrict__ csum) {
    int r = blockIdx.x;
    int t = threadIdx.x;
    int lane = t & 63, w = t >> 6;
    double orig = (t < NCHUNK) ? csum[(long)r * NCHUNK + t] : 0.0;
    double v = orig;
    for (int off = 1; off < 64; off <<= 1) {
        double n = __shfl_up(v, off, 64);
        if (lane >= off) v += n;
    }
    __shared__ double wsum[8];
    if (lane == 63) wsum[w] = v;
    __syncthreads();
    double add = 0.0;
    for (int i = 0; i < w; ++i) add += wsum[i];
    v += add;
    if (t < NCHUNK) csum[(long)r * NCHUNK + t] = v - orig;   // exclusive prefix
}

// ---------------------------------------------------------------------------
// Kernel 3: per-sample phase nu (revolutions mod 1). Bit-identical double
// math to the passing kernels.
// ---------------------------------------------------------------------------
__global__ __launch_bounds__(128) void nu_kernel(
        const float* __restrict__ f0, const double* __restrict__ csum,
        const float* __restrict__ phase, float* __restrict__ nuarr) {
    int bx = blockIdx.x;                 // chunk id
    int r  = bx / NCHUNK;
    int t  = threadIdx.x;
    int lane = t & 63, w = t >> 6;
    long sbase = (long)bx * CHUNK;
    double v = (double)f0[sbase + t];
    for (int off = 1; off < 64; off <<= 1) {
        double n = __shfl_up(v, off, 64);
        if (lane >= off) v += n;
    }
    __shared__ double wsum[2];
    if (lane == 63) wsum[w] = v;
    __syncthreads();
    if (w == 1) v += wsum[0];
    v += csum[bx];
    double x = v * (1.0 / 44100.0) + (double)phase[r] * 0.15915494309189535;
    x -= floor(x);
    nuarr[sbase + t] = (float)x;         // [0,1)
}

// ---------------------------------------------------------------------------
// Kernel 4: oscillator. One block = 512 threads = one chunk of 128 samples;
// lane layout: s = w*16 + (lane>>2), harmonic quarter q = lane&3 (16 harmonics
// per lane). ha has reuse factor 1 -> no LDS staging; direct global loads,
// L1 line-sharing coalesces (4 lanes share each sample's 65-float row).
// Only LDS is the 4.6 KB scale table, built per block. One barrier total.
// Math identical to the passing R2/R3 kernels.
// ---------------------------------------------------------------------------
__global__ __launch_bounds__(512) void osc_kernel(
        const float* __restrict__ f0,
        const float* __restrict__ ha,
        const float* __restrict__ nuarr,
        float* __restrict__ out) {
    int c = blockIdx.x;
    int t = threadIdx.x;
    int lane = t & 63, w = t >> 6;

    __shared__ float tab[TAB_N];         // 4,608 B

    long sbase = (long)c * CHUNK;
    int s  = w * 16 + (lane >> 2);       // sample within chunk
    int q  = lane & 3;                   // harmonic quarter
    int h0 = q * 16;                     // harmonics h0+1 .. h0+16

    // issue per-sample loads early; latency hides under the table build
    float f0v = f0[sbase + s];
    float nu  = nuarr[sbase + s];

    // ---- build scale_fn table in LDS (same values as old table_kernel) ----
    tab[t]       = scale_fn(fmaf((float)t,          0.015625f, -8.0f));
    tab[t + 512] = scale_fn(fmaf((float)(t + 512),  0.015625f, -8.0f));
    if (t < TAB_N - 1024)
        tab[t + 1024] = scale_fn(fmaf((float)(t + 1024), 0.015625f, -8.0f));
    __syncthreads();                     // only barrier in the kernel

    // ---- exact anti-alias cutoff: max h with f0*h < 22050 (f32 semantics) --
    float k0 = floorf(22050.0f / f0v);
    if (f0v * (k0 + 1.0f) < 22050.0f)      k0 += 1.0f;
    else if (!(f0v * k0 < 22050.0f))       k0 -= 1.0f;

    // ---- Chebyshev init: sA=sin((h0+1)θ), sB=sin((h0+2)θ), c2=2cosθ ----
    float c2 = 2.0f * __cosf(6.283185307179586f * nu);
    float m1 = (float)(h0 + 1) * nu; m1 -= floorf(m1);
    float m2 = (float)(h0 + 2) * nu; m2 -= floorf(m2);
    float sA = __sinf(6.283185307179586f * m1);
    float sB = __sinf(6.283185307179586f * m2);

    // this lane's 16 amplitudes, read directly from global (L1-hot lines)
    const float* __restrict__ arow = ha + (sbase + s) * 65 + 1 + h0;

    float S1 = 0.0f, S2 = 0.0f;
    #pragma unroll
    for (int j = 0; j < 16; j += 2) {
        float a0 = arow[j];
        float a1 = arow[j + 1];
        // scale_fn via table interp (identical math to passing kernel)
        float tc0 = fmaf(a0, 64.0f, 512.0f);
        tc0 = fminf(fmaxf(tc0, 0.0f), 1022.99f);
        float fi0 = floorf(tc0); int i0 = (int)fi0; float fr0 = tc0 - fi0;
        float w0 = fmaf(fr0, tab[i0 + 1] - tab[i0], tab[i0]);
        float tc1 = fmaf(a1, 64.0f, 512.0f);
        tc1 = fminf(fmaxf(tc1, 0.0f), 1022.99f);
        float fi1 = floorf(tc1); int i1 = (int)fi1; float fr1 = tc1 - fi1;
        float w1 = fmaf(fr1, tab[i1 + 1] - tab[i1], tab[i1]);

        w0 = ((float)(h0 + 1 + j) <= k0) ? w0 : 0.0f;
        w1 = ((float)(h0 + 2 + j) <= k0) ? w1 : 0.0f;

        S1 += w0; S2 = fmaf(w0, sA, S2);
        S1 += w1; S2 = fmaf(w1, sB, S2);

        float sn1 = fmaf(c2, sB, -sA);       // sin((h0+3+j)θ)
        float sn2 = fmaf(c2, sn1, -sB);      // sin((h0+4+j)θ)
        sA = sn1; sB = sn2;
    }

    // ---- combine the 4 harmonic quarters of each sample ----
    S1 += __shfl_xor(S1, 1, 64);
    S1 += __shfl_xor(S1, 2, 64);
    S2 += __shfl_xor(S2, 1, 64);
    S2 += __shfl_xor(S2, 2, 64);

    if (q == 0) {
        float total = scale_fn(ha[(sbase + s) * 65]);   // exact, once/sample
        out[sbase + s] = total * S2 / (S1 + 1e-5f);
    }
}

// ---------------------------------------------------------------------------
extern "C" void kernel_launch(void* const* d_in, const int* in_sizes, int n_in,
                              void* d_out, int out_size, void* d_ws, size_t ws_size,
                              hipStream_t stream) {
    (void)in_sizes; (void)n_in; (void)out_size; (void)ws_size;
    const float* f0    = (const float*)d_in[0];   // (32, 64000)
    const float* ha    = (const float*)d_in[1];   // (32, 64000, 65)
    const float* phase = (const float*)d_in[2];   // (32,)
    float* out = (float*)d_out;                   // (32, 64000)

    double* csum  = (double*)d_ws;                     // 128,000 B
    float*  nuarr = (float*)((char*)d_ws + 262144);    // 8,192,000 B

    chunk_sum_kernel<<<NCH_TOT, CHUNK, 0, stream>>>(f0, csum);
    chunk_scan_kernel<<<BATCH, 512, 0, stream>>>(csum);
    nu_kernel<<<NCH_TOT, CHUNK, 0, stream>>>(f0, csum, phase, nuarr);
    osc_kernel<<<NCH_TOT, 512, 0, stream>>>(f0, ha, nuarr, out);
}